// Round 1
// baseline (92.679 us; speedup 1.0000x reference)
//
#include <hip/hip_runtime.h>

// LRNN: h_t = g_t * h_{t-1} + (1 - g_t) * x_t along W axis.
// Shapes: (B,H,W,C) = (8,256,256,64) float32, scan over W (axis 2), forward.
// One thread per (b,h,c) sequence: 131072 threads, each serially scans W=256.
// Lane -> c mapping gives fully coalesced 256B/wave accesses at every step.

#define LRNN_B 8
#define LRNN_H 256
#define LRNN_W 256
#define LRNN_C 64

__global__ __launch_bounds__(256) void lrnn_scan_kernel(
    const float* __restrict__ X, const float* __restrict__ G,
    float* __restrict__ out) {
    const int tid = blockIdx.x * blockDim.x + threadIdx.x;  // 0 .. 131071
    const int c   = tid & (LRNN_C - 1);
    const int row = tid >> 6;                // (b*H + h), 0 .. 2047
    // base offset of (row, w=0, c); W*C = 16384, fits int32 (total 2^25 elems)
    int idx = row * (LRNN_W * LRNN_C) + c;

    float h = 0.0f;
#pragma unroll 8
    for (int w = 0; w < LRNN_W; ++w) {
        const float x = X[idx];
        const float g = G[idx];
        // h = g*h + (1-g)*x  ==  g*(h - x) + x   (1 sub + 1 fma)
        h = fmaf(g, h - x, x);
        out[idx] = h;
        idx += LRNN_C;
    }
}

extern "C" void kernel_launch(void* const* d_in, const int* in_sizes, int n_in,
                              void* d_out, int out_size, void* d_ws, size_t ws_size,
                              hipStream_t stream) {
    const float* X = (const float*)d_in[0];
    const float* G = (const float*)d_in[1];
    float* out = (float*)d_out;

    const int total_threads = LRNN_B * LRNN_H * LRNN_C;  // 131072
    const int block = 256;
    const int grid = total_threads / block;              // 512
    lrnn_scan_kernel<<<grid, block, 0, stream>>>(X, G, out);
}

// Round 2
// 87.553 us; speedup vs baseline: 1.0585x; 1.0585x over previous
//
#include <hip/hip_runtime.h>

// LRNN: h_t = g_t * h_{t-1} + (1 - g_t) * x_t along W axis.
// Shapes: (B,H,W,C) = (8,256,256,64) float32, scan over W (axis 2), forward.
// One thread per (b,h,c) sequence; lane -> c gives coalesced 256B/wave.
// R1: explicit double-buffered register prefetch (8-deep batches, two named
// buffers, all compile-time indices) to keep ~32 loads in flight per wave —
// R0 was latency-bound (VALUBusy 1.7%, VGPR=16, HBM at 37% of achievable).

#define LRNN_B 8
#define LRNN_H 256
#define LRNN_W 256
#define LRNN_C 64

__global__ __launch_bounds__(256) void lrnn_scan_kernel(
    const float* __restrict__ X, const float* __restrict__ G,
    float* __restrict__ out) {
    const int tid = blockIdx.x * blockDim.x + threadIdx.x;  // 0 .. 131071
    const int c   = tid & (LRNN_C - 1);
    const int row = tid >> 6;                               // 0 .. 2047
    int idx = row * (LRNN_W * LRNN_C) + c;

    float xa[8], ga[8], xb[8], gb[8];

    // prologue: load batch A (w = 0..7)
#pragma unroll
    for (int j = 0; j < 8; ++j) {
        xa[j] = X[idx + j * LRNN_C];
        ga[j] = G[idx + j * LRNN_C];
    }

    float h = 0.0f;

    // main loop: 15 iterations x 16 elements = 240; epilogue handles last 16
    for (int wb = 0; wb < LRNN_W - 16; wb += 16) {
        // issue batch B loads (w+8 .. w+15)
#pragma unroll
        for (int j = 0; j < 8; ++j) {
            xb[j] = X[idx + (8 + j) * LRNN_C];
            gb[j] = G[idx + (8 + j) * LRNN_C];
        }
        // compute + store batch A
#pragma unroll
        for (int j = 0; j < 8; ++j) {
            h = fmaf(ga[j], h - xa[j], xa[j]);
            out[idx + j * LRNN_C] = h;
        }
        // issue batch A-next loads (w+16 .. w+23)
#pragma unroll
        for (int j = 0; j < 8; ++j) {
            xa[j] = X[idx + (16 + j) * LRNN_C];
            ga[j] = G[idx + (16 + j) * LRNN_C];
        }
        // compute + store batch B
#pragma unroll
        for (int j = 0; j < 8; ++j) {
            h = fmaf(gb[j], h - xb[j], xb[j]);
            out[idx + (8 + j) * LRNN_C] = h;
        }
        idx += 16 * LRNN_C;
    }

    // epilogue: batch A (preloaded, w = 240..247) + batch B (w = 248..255)
#pragma unroll
    for (int j = 0; j < 8; ++j) {
        xb[j] = X[idx + (8 + j) * LRNN_C];
        gb[j] = G[idx + (8 + j) * LRNN_C];
    }
#pragma unroll
    for (int j = 0; j < 8; ++j) {
        h = fmaf(ga[j], h - xa[j], xa[j]);
        out[idx + j * LRNN_C] = h;
    }
#pragma unroll
    for (int j = 0; j < 8; ++j) {
        h = fmaf(gb[j], h - xb[j], xb[j]);
        out[idx + (8 + j) * LRNN_C] = h;
    }
}

extern "C" void kernel_launch(void* const* d_in, const int* in_sizes, int n_in,
                              void* d_out, int out_size, void* d_ws, size_t ws_size,
                              hipStream_t stream) {
    const float* X = (const float*)d_in[0];
    const float* G = (const float*)d_in[1];
    float* out = (float*)d_out;

    const int total_threads = LRNN_B * LRNN_H * LRNN_C;  // 131072
    const int block = 256;
    const int grid = total_threads / block;              // 512
    lrnn_scan_kernel<<<grid, block, 0, stream>>>(X, G, out);
}

// Round 3
// 86.492 us; speedup vs baseline: 1.0715x; 1.0123x over previous
//
#include <hip/hip_runtime.h>

// LRNN: h_t = g_t * h_{t-1} + (1 - g_t) * x_t along W axis.
// (B,H,W,C) = (8,256,256,64) f32, scan over W, forward. Thread per (b,h,c).
// R2: R1's double-buffered prefetch + __builtin_amdgcn_sched_barrier(0)
// after each load batch. R1 showed VGPR=32 -> compiler sank the prefetch
// loads back to their uses (only ~10 loads in flight, 3 TB/s). The fences
// forbid sinking, keeping 16 x 256B loads outstanding per wave during the
// serial-FMA stall, which is enough MLP to saturate HBM at 8 waves/CU.

#define LRNN_B 8
#define LRNN_H 256
#define LRNN_W 256
#define LRNN_C 64

__global__ __launch_bounds__(256) void lrnn_scan_kernel(
    const float* __restrict__ X, const float* __restrict__ G,
    float* __restrict__ out) {
    const int tid = blockIdx.x * blockDim.x + threadIdx.x;  // 0 .. 131071
    const int c   = tid & (LRNN_C - 1);
    const int row = tid >> 6;                               // 0 .. 2047
    int idx = row * (LRNN_W * LRNN_C) + c;

    float xa[8], ga[8], xb[8], gb[8];

    // prologue: load batch A (w = 0..7), pin above everything that follows
#pragma unroll
    for (int j = 0; j < 8; ++j) {
        xa[j] = X[idx + j * LRNN_C];
        ga[j] = G[idx + j * LRNN_C];
    }
    __builtin_amdgcn_sched_barrier(0);

    float h = 0.0f;

    // main loop: 15 iterations x 16 elements = 240; epilogue handles last 16
    for (int wb = 0; wb < LRNN_W - 16; wb += 16) {
        // issue batch B loads (w+8 .. w+15); fence keeps them issued here
#pragma unroll
        for (int j = 0; j < 8; ++j) {
            xb[j] = X[idx + (8 + j) * LRNN_C];
            gb[j] = G[idx + (8 + j) * LRNN_C];
        }
        __builtin_amdgcn_sched_barrier(0);
        // compute + store batch A (waits only on A's loads, issued last iter)
#pragma unroll
        for (int j = 0; j < 8; ++j) {
            h = fmaf(ga[j], h - xa[j], xa[j]);
            out[idx + j * LRNN_C] = h;
        }
        __builtin_amdgcn_sched_barrier(0);
        // issue batch A-next loads (w+16 .. w+23)
#pragma unroll
        for (int j = 0; j < 8; ++j) {
            xa[j] = X[idx + (16 + j) * LRNN_C];
            ga[j] = G[idx + (16 + j) * LRNN_C];
        }
        __builtin_amdgcn_sched_barrier(0);
        // compute + store batch B
#pragma unroll
        for (int j = 0; j < 8; ++j) {
            h = fmaf(gb[j], h - xb[j], xb[j]);
            out[idx + (8 + j) * LRNN_C] = h;
        }
        __builtin_amdgcn_sched_barrier(0);
        idx += 16 * LRNN_C;
    }

    // epilogue: batch A (preloaded, w = 240..247) + batch B (w = 248..255)
#pragma unroll
    for (int j = 0; j < 8; ++j) {
        xb[j] = X[idx + (8 + j) * LRNN_C];
        gb[j] = G[idx + (8 + j) * LRNN_C];
    }
    __builtin_amdgcn_sched_barrier(0);
#pragma unroll
    for (int j = 0; j < 8; ++j) {
        h = fmaf(ga[j], h - xa[j], xa[j]);
        out[idx + j * LRNN_C] = h;
    }
#pragma unroll
    for (int j = 0; j < 8; ++j) {
        h = fmaf(gb[j], h - xb[j], xb[j]);
        out[idx + (8 + j) * LRNN_C] = h;
    }
}

extern "C" void kernel_launch(void* const* d_in, const int* in_sizes, int n_in,
                              void* d_out, int out_size, void* d_ws, size_t ws_size,
                              hipStream_t stream) {
    const float* X = (const float*)d_in[0];
    const float* G = (const float*)d_in[1];
    float* out = (float*)d_out;

    const int total_threads = LRNN_B * LRNN_H * LRNN_C;  // 131072
    const int block = 256;
    const int grid = total_threads / block;              // 512
    lrnn_scan_kernel<<<grid, block, 0, stream>>>(X, G, out);
}

// Round 4
// 83.422 us; speedup vs baseline: 1.1110x; 1.0368x over previous
//
#include <hip/hip_runtime.h>

// LRNN: h_t = g_t * h_{t-1} + (1 - g_t) * x_t along W, (B,H,W,C)=(8,256,256,64) f32.
// R3: chunked scan. R0-R2 were latency-bound (6.4 waves/CU, ~7 loads in flight,
// 3 TB/s); compiler refuses to hold deep prefetch buffers (VGPR stayed 32-36).
// New structure: block = 1024 threads = one (b,h) row; thread (k,c) scans a
// 16-element chunk (local scan hl[] + gate-prefix ap[]), carries exchanged via
// LDS, prefix composed per-thread, fixup h_t = hl_t + ap_t * h_in.
// 2048 blocks -> 2 blocks/CU x 16 waves = 32 waves/CU: TLP does the latency
// hiding instead of per-wave MLP. Same HBM traffic, one barrier.

#define LRNN_W 256
#define LRNN_C 64
#define CHUNK 16
#define NCHUNK 16  // LRNN_W / CHUNK

__global__ __launch_bounds__(1024, 8) void lrnn_scan_kernel(
    const float* __restrict__ X, const float* __restrict__ G,
    float* __restrict__ out) {
    __shared__ float lA[NCHUNK][LRNN_C];  // per-chunk gate product
    __shared__ float lB[NCHUNK][LRNN_C];  // per-chunk local end state

    const int c = threadIdx.x & (LRNN_C - 1);
    const int k = threadIdx.x >> 6;        // chunk index = wave index, 0..15
    const int row = blockIdx.x;            // 0..2047  (b*H + h)
    // max offset = 2047*16384 + 15*1024 + 63 < 2^25, fits int32
    const int base = row * (LRNN_W * LRNN_C) + k * (CHUNK * LRNN_C) + c;

    // Pass A: local scan of the chunk (h_in = 0) + running gate product.
    // h_t = hl[t] + ap[t] * h_in  for the true incoming state h_in.
    float hl[CHUNK], ap[CHUNK];
    float h = 0.0f, a = 1.0f;
#pragma unroll
    for (int t = 0; t < CHUNK; ++t) {
        const float x = X[base + t * LRNN_C];
        const float g = G[base + t * LRNN_C];
        h = fmaf(g, h - x, x);  // g*h + (1-g)*x
        a *= g;
        hl[t] = h;
        ap[t] = a;
    }

    // Carry exchange: (A_k, B_k) per (chunk, channel).
    lA[k][c] = a;
    lB[k][c] = h;
    __syncthreads();

    // Compose incoming state for this chunk: fold chunks 0..k-1 in order.
    // k is wave-uniform -> no divergence inside a wave; lanes read
    // consecutive c -> conflict-free LDS.
    float hin = 0.0f;
    for (int j = 0; j < k; ++j)
        hin = fmaf(lA[j][c], hin, lB[j][c]);

    // Pass B: fixup + store (coalesced 256B per wave per step).
#pragma unroll
    for (int t = 0; t < CHUNK; ++t)
        out[base + t * LRNN_C] = fmaf(ap[t], hin, hl[t]);
}

extern "C" void kernel_launch(void* const* d_in, const int* in_sizes, int n_in,
                              void* d_out, int out_size, void* d_ws, size_t ws_size,
                              hipStream_t stream) {
    const float* X = (const float*)d_in[0];
    const float* G = (const float*)d_in[1];
    float* out = (float*)d_out;

    const int rows = 8 * 256;  // B*H = 2048 blocks, one row per block
    lrnn_scan_kernel<<<rows, NCHUNK * LRNN_C, 0, stream>>>(X, G, out);
}